// Round 8
// baseline (239.818 us; speedup 1.0000x reference)
//
#include <hip/hip_runtime.h>
#include <hip/hip_fp16.h>

#define D_IN 4096
#define FEAT 4096
#define BATCH 4096
#define MAX_SLOTS 64   // capacity per feature (actual ~50); multiple of 8
#define BFEAT 16       // features per emission block (== one gather 16-lane group)
#define RCAP 8         // per-(feature,residue) bucket capacity (u8 entries)
#define OVCAP 16       // overflow pool per feature (u16 entries)

typedef _Float16 h2 __attribute__((ext_vector_type(2)));

__device__ __forceinline__ h2 bc(unsigned u) { return __builtin_bit_cast(h2, u); }

// ---------------------------------------------------------------------------
// Kernel 1a (scan): fully-coalesced float4 scan of w (row-major [D_IN][FEAT]);
// active (i,F) appended to global residue bucket (F, i&15). Bucket entries
// store i>>4 as u8 (low 4 bits implied by the bucket residue).
// ---------------------------------------------------------------------------
__global__ void scan_kernel(const float* __restrict__ w,
                            unsigned int* __restrict__ c16,     // [FEAT*16]
                            unsigned char* __restrict__ rbuf,   // [FEAT*16*RCAP]
                            unsigned int* __restrict__ ocnt,    // [FEAT]
                            unsigned short* __restrict__ ovf) { // [FEAT*OVCAP]
    int t = blockIdx.x * blockDim.x + threadIdx.x;   // one float4 per thread
    float4 v = ((const float4*)w)[t];
    int flat = t * 4;
    float a[4] = {v.x, v.y, v.z, v.w};
#pragma unroll
    for (int c = 0; c < 4; ++c) {
        if (a[c] > 0.0f) {
            int e = flat + c;
            int F = e & (FEAT - 1);
            int i = e >> 12;                         // e / FEAT
            int r = i & 15;
            unsigned int p = atomicAdd(&c16[(F << 4) + r], 1u);
            if (p < RCAP) {
                rbuf[(size_t)((F << 4) + r) * RCAP + p] = (unsigned char)(i >> 4);
            } else {
                unsigned int op = atomicAdd(&ocnt[F], 1u);
                if (op < OVCAP) ovf[(size_t)F * OVCAP + op] = (unsigned short)i;
            }
        }
    }
}

// ---------------------------------------------------------------------------
// Kernel 1b (emit): strict mod-16 bank-phase ordering + WITHIN-WINDOW LOAD
// BALANCE. The 16 features of this block are one gather lane-group; the
// feature processed in lane-slot s targets residue (p+s)&15 at position p
// (slots distinct -> conflict-freedom preserved for ANY permutation).
// Slot assignment: sort by count, slot s <- rank s (even windows by bit6) or
// rank 15-s (odd) -> each gather thread's 4 windows alternate direction,
// giving antithetic small+large sums (wave-max imbalance 15% -> ~5%).
// fmap[f0+s] = feature id for gather indirection (stores stay within the
// same 64B line per row -> coalescing unchanged). Values PRE-SHIFTED (<<4)
// as byte offsets. Output: oct-packed u16, slot pos of feature f at ushort
// offset ((pos>>3)*FEAT + f)*8 + (pos&7). cnt[] written here.
// ---------------------------------------------------------------------------
__global__ __launch_bounds__(256)
void emit_kernel(const unsigned int* __restrict__ c16,
                 const unsigned char* __restrict__ rbuf,
                 const unsigned int* __restrict__ ocnt,
                 const unsigned short* __restrict__ ovf,
                 unsigned int* __restrict__ cnt,
                 unsigned short* __restrict__ idx,
                 unsigned short* __restrict__ fmap) {
    __shared__ __align__(16) unsigned short outl[BFEAT][MAX_SLOTS]; // 2 KB
    __shared__ unsigned short extras[BFEAT][48];
    __shared__ unsigned char  gapsl[BFEAT][48];
    __shared__ int            scnt[BFEAT][16];       // item countdown per (f,r)
    __shared__ unsigned char  kk[BFEAT][16];         // clamped counts
    __shared__ unsigned char  mm[BFEAT][16];         // native-consumed counts
    __shared__ unsigned int   ecnt[BFEAT], gcnt[BFEAT];
    __shared__ unsigned short nn[BFEAT];
    __shared__ unsigned char  slotf[BFEAT];          // feature-local -> lane slot

    const int tid = threadIdx.x;
    const int f0  = blockIdx.x * BFEAT;
    const int f   = tid >> 4, r = tid & 15;
    const int F   = f0 + f;

    if (tid < BFEAT) { ecnt[tid] = 0u; gcnt[tid] = 0u; }
    // zero outl (garbage hygiene): 512 uints, 2 per thread
    ((unsigned int*)outl)[tid] = 0u;
    ((unsigned int*)outl)[tid + 256] = 0u;

    {   // per-residue clamped counts
        unsigned int c = c16[(F << 4) + r];
        int kr = c > RCAP ? RCAP : (int)c;
        kk[f][r] = (unsigned char)kr;
        scnt[f][r] = kr;
    }
    __syncthreads();

    if (r == 0) {                                    // per-feature total
        int s = 0;
#pragma unroll
        for (int q = 0; q < 16; ++q) s += (int)kk[f][q];
        int ov = (int)ocnt[F]; if (ov > OVCAP) ov = OVCAP;
        s += ov;
        if (s > MAX_SLOTS) s = MAX_SLOTS;
        nn[f] = (unsigned short)s;
        cnt[F] = (unsigned int)s;
    }
    __syncthreads();

    if (tid == 0) {                                  // slot assignment (16 elems)
        unsigned char ord[BFEAT];                    // ranks ascending by count
        for (int i = 0; i < BFEAT; ++i) {
            int j = i;
            unsigned char cur = (unsigned char)i;
            while (j > 0 && nn[cur] < nn[ord[j - 1]]) { ord[j] = ord[j - 1]; --j; }
            ord[j] = cur;
        }
        const int wdir = (int)((blockIdx.x >> 6) & 1);
        for (int s = 0; s < BFEAT; ++s) {
            const int fl = (int)ord[wdir ? (15 - s) : s];
            slotf[fl] = (unsigned char)s;
            fmap[f0 + s] = (unsigned short)(f0 + fl);
        }
    }
    __syncthreads();

    {   // native fill: one thread per (f,r); phase keyed by SLOT
        const int sf = (int)slotf[f];
        const int n  = (int)nn[f];
        const int kr = (int)kk[f][r];
        uint2 braw = *reinterpret_cast<const uint2*>(rbuf + (size_t)((F << 4) + r) * RCAP);
        const unsigned char* bs = reinterpret_cast<const unsigned char*>(&braw);
        const int base = (r - sf) & 15;                        // first native position
        const int tgt  = (n >> 4) + (base < (n & 15) ? 1 : 0); // native positions < n
        const int m    = kr < tgt ? kr : tgt;
        mm[f][r] = (unsigned char)m;
        for (int j = 0; j < m; ++j)
            outl[f][base + (j << 4)] = (unsigned short)(((int)bs[j] << 8) | (r << 4));
    }
    __syncthreads();

    // ---- repair pass: one thread per position p -----------------------------
    if (tid < MAX_SLOTS) {
        const int p = tid;
        const int j = p >> 4;
        unsigned used = 0u;
        unsigned gapf = 0u;
#pragma unroll
        for (int ff = 0; ff < BFEAT; ++ff) {
            if (p < (int)nn[ff]) {
                const int rr = (p + (int)slotf[ff]) & 15;
                if (j < (int)mm[ff][rr]) used |= 1u << rr;   // natively filled
                else                     gapf |= 1u << ff;   // gap at (ff,p)
            }
        }
        while (gapf) {
            const int ff = __builtin_ctz(gapf);
            gapf &= gapf - 1;
            const int rr = (p + (int)slotf[ff]) & 15;
            int got = -1, gr = -1;
            for (int dr = 1; dr < 16; ++dr) {        // rotate start: spread depletion
                const int rc = (rr + dr) & 15;
                if ((used >> rc) & 1u) continue;
                const int t = atomicSub(&scnt[ff][rc], 1) - 1;
                if (t >= (int)mm[ff][rc]) { got = t; gr = rc; break; }
            }
            if (got >= 0) {
                const unsigned char item =
                    rbuf[(size_t)(((f0 + ff) << 4) + gr) * RCAP + got];
                outl[ff][p] = (unsigned short)(((int)item << 8) | (gr << 4));
                used |= 1u << gr;
            } else {
                unsigned int g = atomicAdd(&gcnt[ff], 1u);
                if (g < 48) gapsl[ff][g] = (unsigned char)p;
            }
        }
    }
    __syncthreads();

    {   // collect unconsumed surplus items -> extras
        const int lo = (int)mm[f][r];
        int hi = scnt[f][r];
        const int kr = (int)kk[f][r];
        if (hi > kr) hi = kr;
        for (int t = lo; t < hi; ++t) {
            unsigned int e = atomicAdd(&ecnt[f], 1u);
            if (e < 48) {
                const unsigned char item = rbuf[(size_t)((F << 4) + r) * RCAP + t];
                extras[f][e] = (unsigned short)(((int)item << 8) | (r << 4));
            }
        }
    }
    if (r == 0) {                                    // overflow pool -> extras
        int ov = (int)ocnt[F]; if (ov > OVCAP) ov = OVCAP;
        for (int jj = 0; jj < ov; ++jj) {
            unsigned int e = atomicAdd(&ecnt[f], 1u);
            if (e < 48) extras[f][e] = (unsigned short)(ovf[(size_t)F * OVCAP + jj] << 4);
        }
    }
    __syncthreads();

    if (tid < BFEAT) {                               // fallback: fill residual gaps
        const int ff = tid;
        int g = (int)gcnt[ff]; if (g > 48) g = 48;
        int e = (int)ecnt[ff]; if (e > 48) e = 48;
        const int m2 = g < e ? g : e;                // e >= g by construction
        for (int t = 0; t < m2; ++t)
            outl[ff][gapsl[ff][t]] = extras[ff][t];
    }
    __syncthreads();

    if (tid < BFEAT * 8) {                           // oct-pack write out
        const int ff = tid >> 3, o = tid & 7;
        const uint4 v = *reinterpret_cast<const uint4*>(&outl[ff][o << 3]);
        reinterpret_cast<uint4*>(idx)[(size_t)o * FEAT + f0 + ff] = v;
    }
}

// ---------------------------------------------------------------------------
// Gather one oct (8 pre-shifted byte offsets) via ds_read_b128: each read
// serves 8 batch rows. Even indices -> A chains, odd -> B chains.
// ---------------------------------------------------------------------------
__device__ __forceinline__ void do_oct(uint4 p, const char* __restrict__ xtb,
                                       h2& A01, h2& A23, h2& A45, h2& A67,
                                       h2& B01, h2& B23, h2& B45, h2& B67) {
    uint4 v0 = *(const uint4*)(xtb + (p.x & 0xFFF0u));
    uint4 v1 = *(const uint4*)(xtb + (p.x >> 16));
    uint4 v2 = *(const uint4*)(xtb + (p.y & 0xFFF0u));
    uint4 v3 = *(const uint4*)(xtb + (p.y >> 16));
    uint4 v4 = *(const uint4*)(xtb + (p.z & 0xFFF0u));
    uint4 v5 = *(const uint4*)(xtb + (p.z >> 16));
    uint4 v6 = *(const uint4*)(xtb + (p.w & 0xFFF0u));
    uint4 v7 = *(const uint4*)(xtb + (p.w >> 16));
    A01 += bc(v0.x); A23 += bc(v0.y); A45 += bc(v0.z); A67 += bc(v0.w);
    B01 += bc(v1.x); B23 += bc(v1.y); B45 += bc(v1.z); B67 += bc(v1.w);
    A01 += bc(v2.x); A23 += bc(v2.y); A45 += bc(v2.z); A67 += bc(v2.w);
    B01 += bc(v3.x); B23 += bc(v3.y); B45 += bc(v3.z); B67 += bc(v3.w);
    A01 += bc(v4.x); A23 += bc(v4.y); A45 += bc(v4.z); A67 += bc(v4.w);
    B01 += bc(v5.x); B23 += bc(v5.y); B45 += bc(v5.z); B67 += bc(v5.w);
    A01 += bc(v6.x); A23 += bc(v6.y); A45 += bc(v6.z); A67 += bc(v6.w);
    B01 += bc(v7.x); B23 += bc(v7.y); B45 += bc(v7.z); B67 += bc(v7.w);
}

// ---------------------------------------------------------------------------
// Kernel 2: gather-sum, 8 batch rows per block, 1024 threads. Thread tid,
// step k processes feature fmap[tid + k*1024] (load-balanced within each
// 16-feature window -> stores stay 64B-line coalesced). One ds_read_b128
// per gathered index serves 8 rows.
// ---------------------------------------------------------------------------
__global__ __launch_bounds__(1024, 8)
void gather_kernel(const float* __restrict__ x,
                   const unsigned int* __restrict__ cnt,
                   const uint4* __restrict__ q,      // oct-packed u16 byte-offsets
                   const unsigned short* __restrict__ q16,
                   const unsigned short* __restrict__ fmap,
                   float* __restrict__ out) {
    __shared__ uint4 xt[D_IN];                       // 64 KB
    const int tid = threadIdx.x;
    const int b0  = blockIdx.x * 8;
    const float* xb = x + (size_t)b0 * D_IN;

    // Stage 8 rows transposed + fp16 RNE packed. 1024 threads x 4 cols = 4096.
    {
        const int c4 = tid << 2;
        float4 r0 = *(const float4*)(xb + c4);
        float4 r1 = *(const float4*)(xb + c4 + D_IN);
        float4 r2 = *(const float4*)(xb + c4 + 2 * D_IN);
        float4 r3 = *(const float4*)(xb + c4 + 3 * D_IN);
        float4 r4 = *(const float4*)(xb + c4 + 4 * D_IN);
        float4 r5 = *(const float4*)(xb + c4 + 5 * D_IN);
        float4 r6 = *(const float4*)(xb + c4 + 6 * D_IN);
        float4 r7 = *(const float4*)(xb + c4 + 7 * D_IN);
#define PACK_COL(cc, comp)                                          \
        {                                                           \
            __half2 p01 = __floats2half2_rn(r0.comp, r1.comp);      \
            __half2 p23 = __floats2half2_rn(r2.comp, r3.comp);      \
            __half2 p45 = __floats2half2_rn(r4.comp, r5.comp);      \
            __half2 p67 = __floats2half2_rn(r6.comp, r7.comp);      \
            uint4 v;                                                \
            v.x = *(unsigned*)&p01;                                 \
            v.y = *(unsigned*)&p23;                                 \
            v.z = *(unsigned*)&p45;                                 \
            v.w = *(unsigned*)&p67;                                 \
            xt[c4 + cc] = v;                                        \
        }
        PACK_COL(0, x) PACK_COL(1, y) PACK_COL(2, z) PACK_COL(3, w)
#undef PACK_COL
    }
    __syncthreads();

    const char* xtb = (const char*)xt;

#pragma unroll
    for (int k = 0; k < 4; k += 2) {
        const int fA = (int)fmap[tid + k * 1024];
        const int fB = (int)fmap[tid + k * 1024 + 1024];
        int nA = (int)cnt[fA]; if (nA > MAX_SLOTS) nA = MAX_SLOTS;
        int nB = (int)cnt[fB]; if (nB > MAX_SLOTS) nB = MAX_SLOTS;
        const uint4* qA = q + fA;
        const uint4* qB = q + fB;

        h2 aA01 = {0,0}, aA23 = {0,0}, aA45 = {0,0}, aA67 = {0,0};
        h2 bA01 = {0,0}, bA23 = {0,0}, bA45 = {0,0}, bA67 = {0,0};
        h2 aB01 = {0,0}, aB23 = {0,0}, aB45 = {0,0}, aB67 = {0,0};
        h2 bB01 = {0,0}, bB23 = {0,0}, bB45 = {0,0}, bB67 = {0,0};

        const int nqA = nA >> 3, nqB = nB >> 3;
        const int jm = nqA < nqB ? nqA : nqB;
        if (jm > 0) {
            uint4 pA = qA[0];
            uint4 pB = qB[0];
            for (int j = 0; j < jm; ++j) {           // depth-1 list prefetch
                const int jn = (j + 1 < jm) ? j + 1 : j;
                uint4 nxA = qA[(size_t)jn * FEAT];
                uint4 nxB = qB[(size_t)jn * FEAT];
                do_oct(pA, xtb, aA01, aA23, aA45, aA67, bA01, bA23, bA45, bA67);
                do_oct(pB, xtb, aB01, aB23, aB45, aB67, bB01, bB23, bB45, bB67);
                pA = nxA; pB = nxB;
            }
        }
        for (int j = jm; j < nqA; ++j)
            do_oct(qA[(size_t)j * FEAT], xtb, aA01, aA23, aA45, aA67, bA01, bA23, bA45, bA67);
        for (int j = jm; j < nqB; ++j)
            do_oct(qB[(size_t)j * FEAT], xtb, aB01, aB23, aB45, aB67, bB01, bB23, bB45, bB67);

        // tails (n & 7 leftovers; q16 values are byte offsets)
        {
            int rem = nA & 7;
            int base = (nqA * FEAT + fA) * 8;
            for (int t = 0; t < rem; ++t) {
                uint4 v = *(const uint4*)(xtb + q16[base + t]);
                aA01 += bc(v.x); aA23 += bc(v.y); aA45 += bc(v.z); aA67 += bc(v.w);
            }
        }
        {
            int rem = nB & 7;
            int base = (nqB * FEAT + fB) * 8;
            for (int t = 0; t < rem; ++t) {
                uint4 v = *(const uint4*)(xtb + q16[base + t]);
                aB01 += bc(v.x); aB23 += bc(v.y); aB45 += bc(v.z); aB67 += bc(v.w);
            }
        }

        // combine chains in fp32, store coalesced across lanes (within-window
        // permutation keeps each 16-lane group inside one 64B line per row)
        float* oA = out + fA;
        oA[(size_t)(b0 + 0) * FEAT] = (float)aA01[0] + (float)bA01[0];
        oA[(size_t)(b0 + 1) * FEAT] = (float)aA01[1] + (float)bA01[1];
        oA[(size_t)(b0 + 2) * FEAT] = (float)aA23[0] + (float)bA23[0];
        oA[(size_t)(b0 + 3) * FEAT] = (float)aA23[1] + (float)bA23[1];
        oA[(size_t)(b0 + 4) * FEAT] = (float)aA45[0] + (float)bA45[0];
        oA[(size_t)(b0 + 5) * FEAT] = (float)aA45[1] + (float)bA45[1];
        oA[(size_t)(b0 + 6) * FEAT] = (float)aA67[0] + (float)bA67[0];
        oA[(size_t)(b0 + 7) * FEAT] = (float)aA67[1] + (float)bA67[1];
        float* oB = out + fB;
        oB[(size_t)(b0 + 0) * FEAT] = (float)aB01[0] + (float)bB01[0];
        oB[(size_t)(b0 + 1) * FEAT] = (float)aB01[1] + (float)bB01[1];
        oB[(size_t)(b0 + 2) * FEAT] = (float)aB23[0] + (float)bB23[0];
        oB[(size_t)(b0 + 3) * FEAT] = (float)aB23[1] + (float)bB23[1];
        oB[(size_t)(b0 + 4) * FEAT] = (float)aB45[0] + (float)bB45[0];
        oB[(size_t)(b0 + 5) * FEAT] = (float)aB45[1] + (float)bB45[1];
        oB[(size_t)(b0 + 6) * FEAT] = (float)aB67[0] + (float)bB67[0];
        oB[(size_t)(b0 + 7) * FEAT] = (float)aB67[1] + (float)bB67[1];
    }
}

// ---------------------------------------------------------------------------
extern "C" void kernel_launch(void* const* d_in, const int* in_sizes, int n_in,
                              void* d_out, int out_size, void* d_ws, size_t ws_size,
                              hipStream_t stream) {
    const float* x = (const float*)d_in[0];      // (BATCH, D_IN) fp32
    const float* w = (const float*)d_in[1];      // (D_IN, FEAT)  fp32
    float* out = (float*)d_out;                  // (BATCH, FEAT) fp32

    // Workspace layout (1448 KB total):
    //   [cnt:   16KB @ 0     ] [idx: 512KB @ 16K ]
    //   [c16:  256KB @ 528K  ] [ocnt: 16KB @ 784K]  <- one contiguous memset
    //   [rbuf: 512KB @ 800K  ] [ovf: 128KB @ 1312K] [fmap: 8KB @ 1440K]
    char* ws = (char*)d_ws;
    unsigned int*   cnt  = (unsigned int*)  (ws);
    unsigned short* idx  = (unsigned short*)(ws + (16u << 10));
    unsigned int*   c16  = (unsigned int*)  (ws + (528u << 10));
    unsigned int*   ocnt = (unsigned int*)  (ws + (784u << 10));
    unsigned char*  rbuf = (unsigned char*) (ws + (800u << 10));
    unsigned short* ovf  = (unsigned short*)(ws + (1312u << 10));
    unsigned short* fmap = (unsigned short*)(ws + (1440u << 10));

    hipMemsetAsync(c16, 0, (272u << 10), stream);    // c16 + ocnt contiguous

    scan_kernel<<<(D_IN * FEAT / 4) / 256, 256, 0, stream>>>(w, c16, rbuf, ocnt, ovf);
    emit_kernel<<<FEAT / BFEAT, 256, 0, stream>>>(c16, rbuf, ocnt, ovf, cnt, idx, fmap);

    gather_kernel<<<BATCH / 8, 1024, 0, stream>>>(x, cnt, (const uint4*)idx, idx, fmap, out);
}

// Round 9
// 229.333 us; speedup vs baseline: 1.0457x; 1.0457x over previous
//
#include <hip/hip_runtime.h>
#include <hip/hip_fp16.h>

#define D_IN 4096
#define FEAT 4096
#define BATCH 4096
#define MAX_SLOTS 64   // capacity per feature (actual ~50); multiple of 8
#define BFEAT 16       // features per emission block (== one gather 16-lane group)
#define RCAP 8         // per-(feature,residue) bucket capacity (u8 entries)
#define OVCAP 16       // overflow pool per feature (u16 entries)

typedef _Float16 h2 __attribute__((ext_vector_type(2)));

__device__ __forceinline__ h2 bc(unsigned u) { return __builtin_bit_cast(h2, u); }

// ---------------------------------------------------------------------------
// Kernel 1a (scan): fully-coalesced float4 scan of w (row-major [D_IN][FEAT]);
// active (i,F) appended to global residue bucket (F, i&15). Bucket entries
// store i>>4 as u8 (low 4 bits implied by the bucket residue).
// ---------------------------------------------------------------------------
__global__ void scan_kernel(const float* __restrict__ w,
                            unsigned int* __restrict__ c16,     // [FEAT*16]
                            unsigned char* __restrict__ rbuf,   // [FEAT*16*RCAP]
                            unsigned int* __restrict__ ocnt,    // [FEAT]
                            unsigned short* __restrict__ ovf) { // [FEAT*OVCAP]
    int t = blockIdx.x * blockDim.x + threadIdx.x;   // one float4 per thread
    float4 v = ((const float4*)w)[t];
    int flat = t * 4;
    float a[4] = {v.x, v.y, v.z, v.w};
#pragma unroll
    for (int c = 0; c < 4; ++c) {
        if (a[c] > 0.0f) {
            int e = flat + c;
            int F = e & (FEAT - 1);
            int i = e >> 12;                         // e / FEAT
            int r = i & 15;
            unsigned int p = atomicAdd(&c16[(F << 4) + r], 1u);
            if (p < RCAP) {
                rbuf[(size_t)((F << 4) + r) * RCAP + p] = (unsigned char)(i >> 4);
            } else {
                unsigned int op = atomicAdd(&ocnt[F], 1u);
                if (op < OVCAP) ovf[(size_t)F * OVCAP + op] = (unsigned short)i;
            }
        }
    }
}

// ---------------------------------------------------------------------------
// Kernel 1b (emit): strict mod-16 bank-phase reserve fill (R5 structure — the
// proven ~7e6-conflict floor) + within-window load-balance slot permutation.
// The feature in lane-slot s targets residue (p+s)&15 at list position p
// (16 distinct slots -> conflict-freedom preserved under ANY permutation).
// Slot assignment: parallel rank by count; direction alternates with bit 6
// of the window index so each gather thread's 4 windows give antithetic
// small+large sums (wave-max imbalance ~15% -> ~5%). fmap[f0+s] = feature.
// NO repair pass (R7/R8 proved it: 0 conflict gain, +40-50 us latency cost).
// Values PRE-SHIFTED (<<4) as byte offsets into the gather's uint4 LDS
// image. Output: oct-packed u16, slot pos of feature f at ushort offset
// ((pos>>3)*FEAT + f)*8 + (pos&7). cnt[] written here.
// ---------------------------------------------------------------------------
__global__ __launch_bounds__(256)
void emit_kernel(const unsigned int* __restrict__ c16,
                 const unsigned char* __restrict__ rbuf,
                 const unsigned int* __restrict__ ocnt,
                 const unsigned short* __restrict__ ovf,
                 unsigned int* __restrict__ cnt,
                 unsigned short* __restrict__ idx,
                 unsigned short* __restrict__ fmap) {
    __shared__ __align__(16) unsigned short outl[BFEAT][MAX_SLOTS]; // 2 KB
    __shared__ unsigned short extras[BFEAT][48];
    __shared__ unsigned char  gapsl[BFEAT][48];
    __shared__ unsigned char  kk[BFEAT][16];         // clamped counts
    __shared__ unsigned int   ecnt[BFEAT], gcnt[BFEAT];
    __shared__ unsigned short nn[BFEAT];
    __shared__ unsigned char  slotf[BFEAT];          // feature-local -> lane slot

    const int tid = threadIdx.x;
    const int f0  = blockIdx.x * BFEAT;
    const int f   = tid >> 4, r = tid & 15;
    const int F   = f0 + f;

    if (tid < BFEAT) { ecnt[tid] = 0u; gcnt[tid] = 0u; }
    // zero outl (garbage hygiene): 512 uints, 2 per thread
    ((unsigned int*)outl)[tid] = 0u;
    ((unsigned int*)outl)[tid + 256] = 0u;

    {   // per-residue clamped counts
        unsigned int c = c16[(F << 4) + r];
        kk[f][r] = (unsigned char)(c > RCAP ? RCAP : c);
    }
    __syncthreads();

    if (r == 0) {                                    // per-feature total
        int s = 0;
#pragma unroll
        for (int q = 0; q < 16; ++q) s += (int)kk[f][q];
        int ov = (int)ocnt[F]; if (ov > OVCAP) ov = OVCAP;
        s += ov;
        if (s > MAX_SLOTS) s = MAX_SLOTS;
        nn[f] = (unsigned short)s;
        cnt[F] = (unsigned int)s;
    }
    __syncthreads();

    if (tid < BFEAT) {                               // parallel rank -> slot
        const int me = ((int)nn[tid] << 4) | tid;    // tie-break by index
        int rank = 0;
#pragma unroll
        for (int j2 = 0; j2 < BFEAT; ++j2)
            rank += ((((int)nn[j2] << 4) | j2) < me) ? 1 : 0;
        const int wdir = (int)((blockIdx.x >> 6) & 1);
        const int s = wdir ? (15 - rank) : rank;
        slotf[tid] = (unsigned char)s;
        fmap[f0 + s] = (unsigned short)(f0 + tid);
    }
    __syncthreads();

    {   // native fill: one thread per (f,r); phase keyed by SLOT
        const int sf = (int)slotf[f];
        const int n  = (int)nn[f];
        const int kr = (int)kk[f][r];
        uint2 braw = *reinterpret_cast<const uint2*>(rbuf + (size_t)((F << 4) + r) * RCAP);
        const unsigned char* bs = reinterpret_cast<const unsigned char*>(&braw);
        const int base = (r - sf) & 15;                        // first native position
        const int tgt  = (n >> 4) + (base < (n & 15) ? 1 : 0); // native positions < n
        const int m    = kr < tgt ? kr : tgt;
        for (int j = 0; j < m; ++j)
            outl[f][base + (j << 4)] = (unsigned short)(((int)bs[j] << 8) | (r << 4));
        for (int j = m; j < kr; ++j) {               // surplus items -> extras
            unsigned int e = atomicAdd(&ecnt[f], 1u);
            if (e < 48) extras[f][e] = (unsigned short)(((int)bs[j] << 8) | (r << 4));
        }
        for (int j = m; j < tgt; ++j) {              // unfilled positions -> gaps
            unsigned int g = atomicAdd(&gcnt[f], 1u);
            if (g < 48) gapsl[f][g] = (unsigned char)(base + (j << 4));
        }
    }
    if (r == 0) {                                    // overflow pool -> extras
        int ov = (int)ocnt[F]; if (ov > OVCAP) ov = OVCAP;
        for (int jj = 0; jj < ov; ++jj) {
            unsigned int e = atomicAdd(&ecnt[f], 1u);
            if (e < 48) extras[f][e] = (unsigned short)(ovf[(size_t)F * OVCAP + jj] << 4);
        }
    }
    __syncthreads();

    if (tid < BFEAT) {                               // pairwise gap fill
        const int ff = tid;
        int g = (int)gcnt[ff]; if (g > 48) g = 48;
        int e = (int)ecnt[ff]; if (e > 48) e = 48;
        const int m2 = g < e ? g : e;                // e >= g by construction
        for (int t = 0; t < m2; ++t)
            outl[ff][gapsl[ff][t]] = extras[ff][t];
    }
    __syncthreads();

    if (tid < BFEAT * 8) {                           // oct-pack write out
        const int ff = tid >> 3, o = tid & 7;
        const uint4 v = *reinterpret_cast<const uint4*>(&outl[ff][o << 3]);
        reinterpret_cast<uint4*>(idx)[(size_t)o * FEAT + f0 + ff] = v;
    }
}

// ---------------------------------------------------------------------------
// Gather one oct (8 pre-shifted byte offsets) via ds_read_b128: each read
// serves 8 batch rows. Even indices -> A chains, odd -> B chains.
// ---------------------------------------------------------------------------
__device__ __forceinline__ void do_oct(uint4 p, const char* __restrict__ xtb,
                                       h2& A01, h2& A23, h2& A45, h2& A67,
                                       h2& B01, h2& B23, h2& B45, h2& B67) {
    uint4 v0 = *(const uint4*)(xtb + (p.x & 0xFFF0u));
    uint4 v1 = *(const uint4*)(xtb + (p.x >> 16));
    uint4 v2 = *(const uint4*)(xtb + (p.y & 0xFFF0u));
    uint4 v3 = *(const uint4*)(xtb + (p.y >> 16));
    uint4 v4 = *(const uint4*)(xtb + (p.z & 0xFFF0u));
    uint4 v5 = *(const uint4*)(xtb + (p.z >> 16));
    uint4 v6 = *(const uint4*)(xtb + (p.w & 0xFFF0u));
    uint4 v7 = *(const uint4*)(xtb + (p.w >> 16));
    A01 += bc(v0.x); A23 += bc(v0.y); A45 += bc(v0.z); A67 += bc(v0.w);
    B01 += bc(v1.x); B23 += bc(v1.y); B45 += bc(v1.z); B67 += bc(v1.w);
    A01 += bc(v2.x); A23 += bc(v2.y); A45 += bc(v2.z); A67 += bc(v2.w);
    B01 += bc(v3.x); B23 += bc(v3.y); B45 += bc(v3.z); B67 += bc(v3.w);
    A01 += bc(v4.x); A23 += bc(v4.y); A45 += bc(v4.z); A67 += bc(v4.w);
    B01 += bc(v5.x); B23 += bc(v5.y); B45 += bc(v5.z); B67 += bc(v5.w);
    A01 += bc(v6.x); A23 += bc(v6.y); A45 += bc(v6.z); A67 += bc(v6.w);
    B01 += bc(v7.x); B23 += bc(v7.y); B45 += bc(v7.z); B67 += bc(v7.w);
}

// ---------------------------------------------------------------------------
// Kernel 2: gather-sum, 8 batch rows per block, 1024 threads. Thread tid,
// step k processes feature fmap[tid + k*1024] (load-balanced within each
// 16-feature window -> stores stay 64B-line coalesced). One ds_read_b128
// per gathered index serves 8 rows. UNCHANGED from round 8.
// ---------------------------------------------------------------------------
__global__ __launch_bounds__(1024, 8)
void gather_kernel(const float* __restrict__ x,
                   const unsigned int* __restrict__ cnt,
                   const uint4* __restrict__ q,      // oct-packed u16 byte-offsets
                   const unsigned short* __restrict__ q16,
                   const unsigned short* __restrict__ fmap,
                   float* __restrict__ out) {
    __shared__ uint4 xt[D_IN];                       // 64 KB
    const int tid = threadIdx.x;
    const int b0  = blockIdx.x * 8;
    const float* xb = x + (size_t)b0 * D_IN;

    // Stage 8 rows transposed + fp16 RNE packed. 1024 threads x 4 cols = 4096.
    {
        const int c4 = tid << 2;
        float4 r0 = *(const float4*)(xb + c4);
        float4 r1 = *(const float4*)(xb + c4 + D_IN);
        float4 r2 = *(const float4*)(xb + c4 + 2 * D_IN);
        float4 r3 = *(const float4*)(xb + c4 + 3 * D_IN);
        float4 r4 = *(const float4*)(xb + c4 + 4 * D_IN);
        float4 r5 = *(const float4*)(xb + c4 + 5 * D_IN);
        float4 r6 = *(const float4*)(xb + c4 + 6 * D_IN);
        float4 r7 = *(const float4*)(xb + c4 + 7 * D_IN);
#define PACK_COL(cc, comp)                                          \
        {                                                           \
            __half2 p01 = __floats2half2_rn(r0.comp, r1.comp);      \
            __half2 p23 = __floats2half2_rn(r2.comp, r3.comp);      \
            __half2 p45 = __floats2half2_rn(r4.comp, r5.comp);      \
            __half2 p67 = __floats2half2_rn(r6.comp, r7.comp);      \
            uint4 v;                                                \
            v.x = *(unsigned*)&p01;                                 \
            v.y = *(unsigned*)&p23;                                 \
            v.z = *(unsigned*)&p45;                                 \
            v.w = *(unsigned*)&p67;                                 \
            xt[c4 + cc] = v;                                        \
        }
        PACK_COL(0, x) PACK_COL(1, y) PACK_COL(2, z) PACK_COL(3, w)
#undef PACK_COL
    }
    __syncthreads();

    const char* xtb = (const char*)xt;

#pragma unroll
    for (int k = 0; k < 4; k += 2) {
        const int fA = (int)fmap[tid + k * 1024];
        const int fB = (int)fmap[tid + k * 1024 + 1024];
        int nA = (int)cnt[fA]; if (nA > MAX_SLOTS) nA = MAX_SLOTS;
        int nB = (int)cnt[fB]; if (nB > MAX_SLOTS) nB = MAX_SLOTS;
        const uint4* qA = q + fA;
        const uint4* qB = q + fB;

        h2 aA01 = {0,0}, aA23 = {0,0}, aA45 = {0,0}, aA67 = {0,0};
        h2 bA01 = {0,0}, bA23 = {0,0}, bA45 = {0,0}, bA67 = {0,0};
        h2 aB01 = {0,0}, aB23 = {0,0}, aB45 = {0,0}, aB67 = {0,0};
        h2 bB01 = {0,0}, bB23 = {0,0}, bB45 = {0,0}, bB67 = {0,0};

        const int nqA = nA >> 3, nqB = nB >> 3;
        const int jm = nqA < nqB ? nqA : nqB;
        if (jm > 0) {
            uint4 pA = qA[0];
            uint4 pB = qB[0];
            for (int j = 0; j < jm; ++j) {           // depth-1 list prefetch
                const int jn = (j + 1 < jm) ? j + 1 : j;
                uint4 nxA = qA[(size_t)jn * FEAT];
                uint4 nxB = qB[(size_t)jn * FEAT];
                do_oct(pA, xtb, aA01, aA23, aA45, aA67, bA01, bA23, bA45, bA67);
                do_oct(pB, xtb, aB01, aB23, aB45, aB67, bB01, bB23, bB45, bB67);
                pA = nxA; pB = nxB;
            }
        }
        for (int j = jm; j < nqA; ++j)
            do_oct(qA[(size_t)j * FEAT], xtb, aA01, aA23, aA45, aA67, bA01, bA23, bA45, bA67);
        for (int j = jm; j < nqB; ++j)
            do_oct(qB[(size_t)j * FEAT], xtb, aB01, aB23, aB45, aB67, bB01, bB23, bB45, bB67);

        // tails (n & 7 leftovers; q16 values are byte offsets)
        {
            int rem = nA & 7;
            int base = (nqA * FEAT + fA) * 8;
            for (int t = 0; t < rem; ++t) {
                uint4 v = *(const uint4*)(xtb + q16[base + t]);
                aA01 += bc(v.x); aA23 += bc(v.y); aA45 += bc(v.z); aA67 += bc(v.w);
            }
        }
        {
            int rem = nB & 7;
            int base = (nqB * FEAT + fB) * 8;
            for (int t = 0; t < rem; ++t) {
                uint4 v = *(const uint4*)(xtb + q16[base + t]);
                aB01 += bc(v.x); aB23 += bc(v.y); aB45 += bc(v.z); aB67 += bc(v.w);
            }
        }

        // combine chains in fp32, store coalesced across lanes (within-window
        // permutation keeps each 16-lane group inside one 64B line per row)
        float* oA = out + fA;
        oA[(size_t)(b0 + 0) * FEAT] = (float)aA01[0] + (float)bA01[0];
        oA[(size_t)(b0 + 1) * FEAT] = (float)aA01[1] + (float)bA01[1];
        oA[(size_t)(b0 + 2) * FEAT] = (float)aA23[0] + (float)bA23[0];
        oA[(size_t)(b0 + 3) * FEAT] = (float)aA23[1] + (float)bA23[1];
        oA[(size_t)(b0 + 4) * FEAT] = (float)aA45[0] + (float)bA45[0];
        oA[(size_t)(b0 + 5) * FEAT] = (float)aA45[1] + (float)bA45[1];
        oA[(size_t)(b0 + 6) * FEAT] = (float)aA67[0] + (float)bA67[0];
        oA[(size_t)(b0 + 7) * FEAT] = (float)aA67[1] + (float)bA67[1];
        float* oB = out + fB;
        oB[(size_t)(b0 + 0) * FEAT] = (float)aB01[0] + (float)bB01[0];
        oB[(size_t)(b0 + 1) * FEAT] = (float)aB01[1] + (float)bB01[1];
        oB[(size_t)(b0 + 2) * FEAT] = (float)aB23[0] + (float)bB23[0];
        oB[(size_t)(b0 + 3) * FEAT] = (float)aB23[1] + (float)bB23[1];
        oB[(size_t)(b0 + 4) * FEAT] = (float)aB45[0] + (float)bB45[0];
        oB[(size_t)(b0 + 5) * FEAT] = (float)aB45[1] + (float)bB45[1];
        oB[(size_t)(b0 + 6) * FEAT] = (float)aB67[0] + (float)bB67[0];
        oB[(size_t)(b0 + 7) * FEAT] = (float)aB67[1] + (float)bB67[1];
    }
}

// ---------------------------------------------------------------------------
extern "C" void kernel_launch(void* const* d_in, const int* in_sizes, int n_in,
                              void* d_out, int out_size, void* d_ws, size_t ws_size,
                              hipStream_t stream) {
    const float* x = (const float*)d_in[0];      // (BATCH, D_IN) fp32
    const float* w = (const float*)d_in[1];      // (D_IN, FEAT)  fp32
    float* out = (float*)d_out;                  // (BATCH, FEAT) fp32

    // Workspace layout (1448 KB total):
    //   [cnt:   16KB @ 0     ] [idx: 512KB @ 16K ]
    //   [c16:  256KB @ 528K  ] [ocnt: 16KB @ 784K]  <- one contiguous memset
    //   [rbuf: 512KB @ 800K  ] [ovf: 128KB @ 1312K] [fmap: 8KB @ 1440K]
    char* ws = (char*)d_ws;
    unsigned int*   cnt  = (unsigned int*)  (ws);
    unsigned short* idx  = (unsigned short*)(ws + (16u << 10));
    unsigned int*   c16  = (unsigned int*)  (ws + (528u << 10));
    unsigned int*   ocnt = (unsigned int*)  (ws + (784u << 10));
    unsigned char*  rbuf = (unsigned char*) (ws + (800u << 10));
    unsigned short* ovf  = (unsigned short*)(ws + (1312u << 10));
    unsigned short* fmap = (unsigned short*)(ws + (1440u << 10));

    hipMemsetAsync(c16, 0, (272u << 10), stream);    // c16 + ocnt contiguous

    scan_kernel<<<(D_IN * FEAT / 4) / 256, 256, 0, stream>>>(w, c16, rbuf, ocnt, ovf);
    emit_kernel<<<FEAT / BFEAT, 256, 0, stream>>>(c16, rbuf, ocnt, ovf, cnt, idx, fmap);

    gather_kernel<<<BATCH / 8, 1024, 0, stream>>>(x, cnt, (const uint4*)idx, idx, fmap, out);
}

// Round 10
// 228.677 us; speedup vs baseline: 1.0487x; 1.0029x over previous
//
#include <hip/hip_runtime.h>
#include <hip/hip_fp16.h>

#define D_IN 4096
#define FEAT 4096
#define BATCH 4096
#define MAX_SLOTS 64   // capacity per feature (actual ~50); multiple of 8
#define BFEAT 16       // features per emission block (== one gather 16-lane group)
#define RCAP 8         // per-(feature,residue) bucket capacity (u8 entries)
#define OVCAP 16       // overflow pool per feature (u16 entries)

typedef _Float16 h2 __attribute__((ext_vector_type(2)));

__device__ __forceinline__ h2 bc(unsigned u) { return __builtin_bit_cast(h2, u); }

// ---------------------------------------------------------------------------
// Kernel 1a (scan): fully-coalesced float4 scan of w (row-major [D_IN][FEAT]);
// active (i,F) appended to global residue bucket (F, i&15). Bucket entries
// store i>>4 as u8 (low 4 bits implied by the bucket residue).
// ---------------------------------------------------------------------------
__global__ void scan_kernel(const float* __restrict__ w,
                            unsigned int* __restrict__ c16,     // [FEAT*16]
                            unsigned char* __restrict__ rbuf,   // [FEAT*16*RCAP]
                            unsigned int* __restrict__ ocnt,    // [FEAT]
                            unsigned short* __restrict__ ovf) { // [FEAT*OVCAP]
    int t = blockIdx.x * blockDim.x + threadIdx.x;   // one float4 per thread
    float4 v = ((const float4*)w)[t];
    int flat = t * 4;
    float a[4] = {v.x, v.y, v.z, v.w};
#pragma unroll
    for (int c = 0; c < 4; ++c) {
        if (a[c] > 0.0f) {
            int e = flat + c;
            int F = e & (FEAT - 1);
            int i = e >> 12;                         // e / FEAT
            int r = i & 15;
            unsigned int p = atomicAdd(&c16[(F << 4) + r], 1u);
            if (p < RCAP) {
                rbuf[(size_t)((F << 4) + r) * RCAP + p] = (unsigned char)(i >> 4);
            } else {
                unsigned int op = atomicAdd(&ocnt[F], 1u);
                if (op < OVCAP) ovf[(size_t)F * OVCAP + op] = (unsigned short)i;
            }
        }
    }
}

// ---------------------------------------------------------------------------
// Kernel 1b (emit): strict mod-16 bank-phase reserve fill + RANK-MATCHED
// load-balance slot permutation. The feature in lane-slot s targets residue
// (p+s)&15 at list position p (16 distinct slots -> conflict-freedom under
// ANY permutation, for lanes at the SAME p). Slot direction keys on BIT 7 of
// the window index: a gather k-pair reads windows (w, w+64) which share bit7
// -> SAME direction -> fA,fB are same-ranked (nqA~nqB: jm covers almost all
// octs, leftover loops ~empty -> lanes stay position-aligned, full ILP),
// while k=0 windows (bit7=0, ascending) vs k=2 windows (bit7=1, descending)
// are antithetic -> thread total = 2*cnt(rank s)+2*cnt(rank 15-s), balanced.
// [R9 lesson: bit-6 keying made pairs opposite-ranked; the big leftover loops
// ran lanes at different p -> +0.9e6 conflicts and lost ILP.]
// Values PRE-SHIFTED (<<4) as byte offsets. Output: oct-packed u16, slot pos
// of feature f at ushort offset ((pos>>3)*FEAT + f)*8 + (pos&7). cnt[] here.
// ---------------------------------------------------------------------------
__global__ __launch_bounds__(256)
void emit_kernel(const unsigned int* __restrict__ c16,
                 const unsigned char* __restrict__ rbuf,
                 const unsigned int* __restrict__ ocnt,
                 const unsigned short* __restrict__ ovf,
                 unsigned int* __restrict__ cnt,
                 unsigned short* __restrict__ idx,
                 unsigned short* __restrict__ fmap) {
    __shared__ __align__(16) unsigned short outl[BFEAT][MAX_SLOTS]; // 2 KB
    __shared__ unsigned short extras[BFEAT][48];
    __shared__ unsigned char  gapsl[BFEAT][48];
    __shared__ unsigned char  kk[BFEAT][16];         // clamped counts
    __shared__ unsigned int   ecnt[BFEAT], gcnt[BFEAT];
    __shared__ unsigned short nn[BFEAT];
    __shared__ unsigned char  slotf[BFEAT];          // feature-local -> lane slot

    const int tid = threadIdx.x;
    const int f0  = blockIdx.x * BFEAT;
    const int f   = tid >> 4, r = tid & 15;
    const int F   = f0 + f;

    if (tid < BFEAT) { ecnt[tid] = 0u; gcnt[tid] = 0u; }
    // zero outl (garbage hygiene): 512 uints, 2 per thread
    ((unsigned int*)outl)[tid] = 0u;
    ((unsigned int*)outl)[tid + 256] = 0u;

    {   // per-residue clamped counts
        unsigned int c = c16[(F << 4) + r];
        kk[f][r] = (unsigned char)(c > RCAP ? RCAP : c);
    }
    __syncthreads();

    if (r == 0) {                                    // per-feature total
        int s = 0;
#pragma unroll
        for (int q = 0; q < 16; ++q) s += (int)kk[f][q];
        int ov = (int)ocnt[F]; if (ov > OVCAP) ov = OVCAP;
        s += ov;
        if (s > MAX_SLOTS) s = MAX_SLOTS;
        nn[f] = (unsigned short)s;
        cnt[F] = (unsigned int)s;
    }
    __syncthreads();

    if (tid < BFEAT) {                               // parallel rank -> slot
        const int me = ((int)nn[tid] << 4) | tid;    // tie-break by index
        int rank = 0;
#pragma unroll
        for (int j2 = 0; j2 < BFEAT; ++j2)
            rank += ((((int)nn[j2] << 4) | j2) < me) ? 1 : 0;
        const int wdir = (int)((blockIdx.x >> 7) & 1);   // BIT 7: pair-matched ranks
        const int s = wdir ? (15 - rank) : rank;
        slotf[tid] = (unsigned char)s;
        fmap[f0 + s] = (unsigned short)(f0 + tid);
    }
    __syncthreads();

    {   // native fill: one thread per (f,r); phase keyed by SLOT
        const int sf = (int)slotf[f];
        const int n  = (int)nn[f];
        const int kr = (int)kk[f][r];
        uint2 braw = *reinterpret_cast<const uint2*>(rbuf + (size_t)((F << 4) + r) * RCAP);
        const unsigned char* bs = reinterpret_cast<const unsigned char*>(&braw);
        const int base = (r - sf) & 15;                        // first native position
        const int tgt  = (n >> 4) + (base < (n & 15) ? 1 : 0); // native positions < n
        const int m    = kr < tgt ? kr : tgt;
        for (int j = 0; j < m; ++j)
            outl[f][base + (j << 4)] = (unsigned short)(((int)bs[j] << 8) | (r << 4));
        for (int j = m; j < kr; ++j) {               // surplus items -> extras
            unsigned int e = atomicAdd(&ecnt[f], 1u);
            if (e < 48) extras[f][e] = (unsigned short)(((int)bs[j] << 8) | (r << 4));
        }
        for (int j = m; j < tgt; ++j) {              // unfilled positions -> gaps
            unsigned int g = atomicAdd(&gcnt[f], 1u);
            if (g < 48) gapsl[f][g] = (unsigned char)(base + (j << 4));
        }
    }
    if (r == 0) {                                    // overflow pool -> extras
        int ov = (int)ocnt[F]; if (ov > OVCAP) ov = OVCAP;
        for (int jj = 0; jj < ov; ++jj) {
            unsigned int e = atomicAdd(&ecnt[f], 1u);
            if (e < 48) extras[f][e] = (unsigned short)(ovf[(size_t)F * OVCAP + jj] << 4);
        }
    }
    __syncthreads();

    if (tid < BFEAT) {                               // pairwise gap fill
        const int ff = tid;
        int g = (int)gcnt[ff]; if (g > 48) g = 48;
        int e = (int)ecnt[ff]; if (e > 48) e = 48;
        const int m2 = g < e ? g : e;                // e >= g by construction
        for (int t = 0; t < m2; ++t)
            outl[ff][gapsl[ff][t]] = extras[ff][t];
    }
    __syncthreads();

    if (tid < BFEAT * 8) {                           // oct-pack write out
        const int ff = tid >> 3, o = tid & 7;
        const uint4 v = *reinterpret_cast<const uint4*>(&outl[ff][o << 3]);
        reinterpret_cast<uint4*>(idx)[(size_t)o * FEAT + f0 + ff] = v;
    }
}

// ---------------------------------------------------------------------------
// Gather one oct (8 pre-shifted byte offsets) via ds_read_b128: each read
// serves 8 batch rows. Even indices -> A chains, odd -> B chains.
// ---------------------------------------------------------------------------
__device__ __forceinline__ void do_oct(uint4 p, const char* __restrict__ xtb,
                                       h2& A01, h2& A23, h2& A45, h2& A67,
                                       h2& B01, h2& B23, h2& B45, h2& B67) {
    uint4 v0 = *(const uint4*)(xtb + (p.x & 0xFFF0u));
    uint4 v1 = *(const uint4*)(xtb + (p.x >> 16));
    uint4 v2 = *(const uint4*)(xtb + (p.y & 0xFFF0u));
    uint4 v3 = *(const uint4*)(xtb + (p.y >> 16));
    uint4 v4 = *(const uint4*)(xtb + (p.z & 0xFFF0u));
    uint4 v5 = *(const uint4*)(xtb + (p.z >> 16));
    uint4 v6 = *(const uint4*)(xtb + (p.w & 0xFFF0u));
    uint4 v7 = *(const uint4*)(xtb + (p.w >> 16));
    A01 += bc(v0.x); A23 += bc(v0.y); A45 += bc(v0.z); A67 += bc(v0.w);
    B01 += bc(v1.x); B23 += bc(v1.y); B45 += bc(v1.z); B67 += bc(v1.w);
    A01 += bc(v2.x); A23 += bc(v2.y); A45 += bc(v2.z); A67 += bc(v2.w);
    B01 += bc(v3.x); B23 += bc(v3.y); B45 += bc(v3.z); B67 += bc(v3.w);
    A01 += bc(v4.x); A23 += bc(v4.y); A45 += bc(v4.z); A67 += bc(v4.w);
    B01 += bc(v5.x); B23 += bc(v5.y); B45 += bc(v5.z); B67 += bc(v5.w);
    A01 += bc(v6.x); A23 += bc(v6.y); A45 += bc(v6.z); A67 += bc(v6.w);
    B01 += bc(v7.x); B23 += bc(v7.y); B45 += bc(v7.z); B67 += bc(v7.w);
}

// ---------------------------------------------------------------------------
// Kernel 2: gather-sum, 8 batch rows per block, 1024 threads. Thread tid,
// step k processes feature fmap[tid + k*1024] (rank-matched pairs within a
// k-step; antithetic across k-steps; stores stay 64B-line coalesced). One
// ds_read_b128 per gathered index serves 8 rows. UNCHANGED from round 9.
// ---------------------------------------------------------------------------
__global__ __launch_bounds__(1024, 8)
void gather_kernel(const float* __restrict__ x,
                   const unsigned int* __restrict__ cnt,
                   const uint4* __restrict__ q,      // oct-packed u16 byte-offsets
                   const unsigned short* __restrict__ q16,
                   const unsigned short* __restrict__ fmap,
                   float* __restrict__ out) {
    __shared__ uint4 xt[D_IN];                       // 64 KB
    const int tid = threadIdx.x;
    const int b0  = blockIdx.x * 8;
    const float* xb = x + (size_t)b0 * D_IN;

    // Stage 8 rows transposed + fp16 RNE packed. 1024 threads x 4 cols = 4096.
    {
        const int c4 = tid << 2;
        float4 r0 = *(const float4*)(xb + c4);
        float4 r1 = *(const float4*)(xb + c4 + D_IN);
        float4 r2 = *(const float4*)(xb + c4 + 2 * D_IN);
        float4 r3 = *(const float4*)(xb + c4 + 3 * D_IN);
        float4 r4 = *(const float4*)(xb + c4 + 4 * D_IN);
        float4 r5 = *(const float4*)(xb + c4 + 5 * D_IN);
        float4 r6 = *(const float4*)(xb + c4 + 6 * D_IN);
        float4 r7 = *(const float4*)(xb + c4 + 7 * D_IN);
#define PACK_COL(cc, comp)                                          \
        {                                                           \
            __half2 p01 = __floats2half2_rn(r0.comp, r1.comp);      \
            __half2 p23 = __floats2half2_rn(r2.comp, r3.comp);      \
            __half2 p45 = __floats2half2_rn(r4.comp, r5.comp);      \
            __half2 p67 = __floats2half2_rn(r6.comp, r7.comp);      \
            uint4 v;                                                \
            v.x = *(unsigned*)&p01;                                 \
            v.y = *(unsigned*)&p23;                                 \
            v.z = *(unsigned*)&p45;                                 \
            v.w = *(unsigned*)&p67;                                 \
            xt[c4 + cc] = v;                                        \
        }
        PACK_COL(0, x) PACK_COL(1, y) PACK_COL(2, z) PACK_COL(3, w)
#undef PACK_COL
    }
    __syncthreads();

    const char* xtb = (const char*)xt;

#pragma unroll
    for (int k = 0; k < 4; k += 2) {
        const int fA = (int)fmap[tid + k * 1024];
        const int fB = (int)fmap[tid + k * 1024 + 1024];
        int nA = (int)cnt[fA]; if (nA > MAX_SLOTS) nA = MAX_SLOTS;
        int nB = (int)cnt[fB]; if (nB > MAX_SLOTS) nB = MAX_SLOTS;
        const uint4* qA = q + fA;
        const uint4* qB = q + fB;

        h2 aA01 = {0,0}, aA23 = {0,0}, aA45 = {0,0}, aA67 = {0,0};
        h2 bA01 = {0,0}, bA23 = {0,0}, bA45 = {0,0}, bA67 = {0,0};
        h2 aB01 = {0,0}, aB23 = {0,0}, aB45 = {0,0}, aB67 = {0,0};
        h2 bB01 = {0,0}, bB23 = {0,0}, bB45 = {0,0}, bB67 = {0,0};

        const int nqA = nA >> 3, nqB = nB >> 3;
        const int jm = nqA < nqB ? nqA : nqB;
        if (jm > 0) {
            uint4 pA = qA[0];
            uint4 pB = qB[0];
            for (int j = 0; j < jm; ++j) {           // depth-1 list prefetch
                const int jn = (j + 1 < jm) ? j + 1 : j;
                uint4 nxA = qA[(size_t)jn * FEAT];
                uint4 nxB = qB[(size_t)jn * FEAT];
                do_oct(pA, xtb, aA01, aA23, aA45, aA67, bA01, bA23, bA45, bA67);
                do_oct(pB, xtb, aB01, aB23, aB45, aB67, bB01, bB23, bB45, bB67);
                pA = nxA; pB = nxB;
            }
        }
        for (int j = jm; j < nqA; ++j)
            do_oct(qA[(size_t)j * FEAT], xtb, aA01, aA23, aA45, aA67, bA01, bA23, bA45, bA67);
        for (int j = jm; j < nqB; ++j)
            do_oct(qB[(size_t)j * FEAT], xtb, aB01, aB23, aB45, aB67, bB01, bB23, bB45, bB67);

        // tails (n & 7 leftovers; q16 values are byte offsets)
        {
            int rem = nA & 7;
            int base = (nqA * FEAT + fA) * 8;
            for (int t = 0; t < rem; ++t) {
                uint4 v = *(const uint4*)(xtb + q16[base + t]);
                aA01 += bc(v.x); aA23 += bc(v.y); aA45 += bc(v.z); aA67 += bc(v.w);
            }
        }
        {
            int rem = nB & 7;
            int base = (nqB * FEAT + fB) * 8;
            for (int t = 0; t < rem; ++t) {
                uint4 v = *(const uint4*)(xtb + q16[base + t]);
                aB01 += bc(v.x); aB23 += bc(v.y); aB45 += bc(v.z); aB67 += bc(v.w);
            }
        }

        // combine chains in fp32, store coalesced across lanes (within-window
        // permutation keeps each 16-lane group inside one 64B line per row)
        float* oA = out + fA;
        oA[(size_t)(b0 + 0) * FEAT] = (float)aA01[0] + (float)bA01[0];
        oA[(size_t)(b0 + 1) * FEAT] = (float)aA01[1] + (float)bA01[1];
        oA[(size_t)(b0 + 2) * FEAT] = (float)aA23[0] + (float)bA23[0];
        oA[(size_t)(b0 + 3) * FEAT] = (float)aA23[1] + (float)bA23[1];
        oA[(size_t)(b0 + 4) * FEAT] = (float)aA45[0] + (float)bA45[0];
        oA[(size_t)(b0 + 5) * FEAT] = (float)aA45[1] + (float)bA45[1];
        oA[(size_t)(b0 + 6) * FEAT] = (float)aA67[0] + (float)bA67[0];
        oA[(size_t)(b0 + 7) * FEAT] = (float)aA67[1] + (float)bA67[1];
        float* oB = out + fB;
        oB[(size_t)(b0 + 0) * FEAT] = (float)aB01[0] + (float)bB01[0];
        oB[(size_t)(b0 + 1) * FEAT] = (float)aB01[1] + (float)bB01[1];
        oB[(size_t)(b0 + 2) * FEAT] = (float)aB23[0] + (float)bB23[0];
        oB[(size_t)(b0 + 3) * FEAT] = (float)aB23[1] + (float)bB23[1];
        oB[(size_t)(b0 + 4) * FEAT] = (float)aB45[0] + (float)bB45[0];
        oB[(size_t)(b0 + 5) * FEAT] = (float)aB45[1] + (float)bB45[1];
        oB[(size_t)(b0 + 6) * FEAT] = (float)aB67[0] + (float)bB67[0];
        oB[(size_t)(b0 + 7) * FEAT] = (float)aB67[1] + (float)bB67[1];
    }
}

// ---------------------------------------------------------------------------
extern "C" void kernel_launch(void* const* d_in, const int* in_sizes, int n_in,
                              void* d_out, int out_size, void* d_ws, size_t ws_size,
                              hipStream_t stream) {
    const float* x = (const float*)d_in[0];      // (BATCH, D_IN) fp32
    const float* w = (const float*)d_in[1];      // (D_IN, FEAT)  fp32
    float* out = (float*)d_out;                  // (BATCH, FEAT) fp32

    // Workspace layout (1448 KB total):
    //   [cnt:   16KB @ 0     ] [idx: 512KB @ 16K ]
    //   [c16:  256KB @ 528K  ] [ocnt: 16KB @ 784K]  <- one contiguous memset
    //   [rbuf: 512KB @ 800K  ] [ovf: 128KB @ 1312K] [fmap: 8KB @ 1440K]
    char* ws = (char*)d_ws;
    unsigned int*   cnt  = (unsigned int*)  (ws);
    unsigned short* idx  = (unsigned short*)(ws + (16u << 10));
    unsigned int*   c16  = (unsigned int*)  (ws + (528u << 10));
    unsigned int*   ocnt = (unsigned int*)  (ws + (784u << 10));
    unsigned char*  rbuf = (unsigned char*) (ws + (800u << 10));
    unsigned short* ovf  = (unsigned short*)(ws + (1312u << 10));
    unsigned short* fmap = (unsigned short*)(ws + (1440u << 10));

    hipMemsetAsync(c16, 0, (272u << 10), stream);    // c16 + ocnt contiguous

    scan_kernel<<<(D_IN * FEAT / 4) / 256, 256, 0, stream>>>(w, c16, rbuf, ocnt, ovf);
    emit_kernel<<<FEAT / BFEAT, 256, 0, stream>>>(c16, rbuf, ocnt, ovf, cnt, idx, fmap);

    gather_kernel<<<BATCH / 8, 1024, 0, stream>>>(x, cnt, (const uint4*)idx, idx, fmap, out);
}